// Round 19
// baseline (36.662 us; speedup 1.0000x reference)
//
#include <hip/hip_runtime.h>
#include <hip/hip_bf16.h>
#include <math.h>

// Problem constants (fixed by setup_inputs)
static constexpr int Cc   = 16;   // C
static constexpr int COc  = 16;   // CO
static constexpr int Hh   = 4;    // heads
static constexpr int CPWc = 32;   // 2*C
static constexpr int NTH  = 256;  // precompute block size
static constexpr int MTH  = 256;  // main block size (4 waves, 2 rows)
static constexpr int TFH  = 768;  // f16 elements per packed 16-k tile (1.5 KB)
static constexpr float LOG2E = 1.44269504088896340736f;

typedef _Float16 f16x2 __attribute__((ext_vector_type(2)));
typedef _Float16 f16x8 __attribute__((ext_vector_type(8)));   // 4 VGPR
typedef __attribute__((ext_vector_type(4))) float f32x4v;     // MFMA C/D

union F4 { float4 v; float f[4]; };
// f16 octet with fully NAMED pair members (no runtime-indexed ext_vector
// arrays -> no scratch demotion; r3 lesson).
union H8 {
  f16x8 v8;
  struct { f16x2 q0, q1, q2, q3; } p;
  float4 f4;
};

__device__ __forceinline__ ushort f2h(float x) {
  _Float16 h = (_Float16)x;
  ushort u;
  __builtin_memcpy(&u, &h, 2);
  return u;
}
__device__ __forceinline__ f16x2 relu2(f16x2 x) {
  return __builtin_elementwise_max(x, (f16x2)(_Float16)0);
}

// ---------------------------------------------------------------------------
// Kernel 1: per-row first-layer projections (fp32 math, validated r1-r17),
// 4 threads per row; cP stored in F16 (validated r14-r17).
// cP f16 layout per 16-k tile (768 f16 = 1.5 KB):
//   [  0,512): lane l=g*16+m -> cW[k=T*16+m][g*8 .. g*8+8) as 8 f16 (16B)
//   [512,768): lane l&31     -> cV[k][gg*8 .. gg*8+8)      (gg = (l>>4)&1)
// Pack block (nRowBlocks): w2f REPLICATED cols B[k][n] = w2[k][n>>2],
// SCALED by LOG2E (exp(relu(x)) = exp2(relu(x*log2e)) since relu commutes
// with positive scaling -> main uses exp2f, saving a v_mul per p);
// v2f = 0.5*v2 duplicated into both K-halves (A duplicates hv -> exact).
// R16 note: cooperative fusion FAILED on this harness -> two kernels.
// R18 note: __exp2f is not a HIP device function (glibc macro collision) —
// use exp2f (lowers to v_exp_f32).
// ---------------------------------------------------------------------------
__global__ __launch_bounds__(NTH) void ppa_precompute(
    const float* __restrict__ xq, const float* __restrict__ xk,
    const float* __restrict__ w1, const float* __restrict__ b1,
    const float* __restrict__ v1, const float* __restrict__ bv1,
    const float* __restrict__ w2, const float* __restrict__ v2,
    float* __restrict__ aW, float* __restrict__ aV,
    ushort* __restrict__ cP,
    ushort* __restrict__ w2f, ushort* __restrict__ v2f,
    int BN, int BK, int Nk, int nRowBlocks) {
  const int t = threadIdx.x;

  if (blockIdx.x == nRowBlocks) {  // packing block
    if (t < 64) {
      const int n = t & 15, g = t >> 4;
#pragma unroll
      for (int i = 0; i < 8; ++i) {
        const int k = g * 8 + i;
        w2f[t * 8 + i] = f2h(LOG2E * w2[k * Hh + (n >> 2)]);  // replicated+scaled
        v2f[t * 8 + i] = f2h(0.5f * v2[(k & 15) * COc + n]);
      }
    }
    return;
  }

  __shared__ float sw1[CPWc * CPWc];
  __shared__ float sv1[CPWc * COc];
  __shared__ float sb1[CPWc];
  __shared__ float sbv1[COc];
  for (int i = t; i < CPWc * CPWc; i += NTH) sw1[i] = w1[i];
  for (int i = t; i < CPWc * COc; i += NTH) sv1[i] = v1[i];
  if (t < CPWc) sb1[t] = b1[t];
  if (t < COc) sbv1[t] = bv1[t];
  __syncthreads();

  const int r = blockIdx.x * 64 + (t >> 2);
  const int sub = t & 3;
  if (r >= BN + BK) return;
  const bool isQ = (r < BN);
  const int rr = isQ ? r : (r - BN);
  const float* src = isQ ? (xq + (size_t)rr * Cc) : (xk + (size_t)rr * Cc);

  float x[Cc];
#pragma unroll
  for (int i = 0; i < Cc; i += 4) {
    float4 v = *reinterpret_cast<const float4*>(src + i);
    x[i] = v.x; x[i + 1] = v.y; x[i + 2] = v.z; x[i + 3] = v.w;
  }

  if (isQ) {
    F4 o0, o1, ov;
#pragma unroll
    for (int jj = 0; jj < 8; ++jj) {
      const int j = sub * 8 + jj;
      float acc = sb1[j];
#pragma unroll
      for (int i = 0; i < Cc; ++i)
        acc += x[i] * (sw1[i * CPWc + j] - sw1[(i + Cc) * CPWc + j]);
      if (jj < 4) o0.f[jj] = acc; else o1.f[jj - 4] = acc;
    }
#pragma unroll
    for (int jj = 0; jj < 4; ++jj) {
      const int j = sub * 4 + jj;
      float acc = sbv1[j];
#pragma unroll
      for (int i = 0; i < Cc; ++i)
        acc += x[i] * (sv1[i * COc + j] - sv1[(i + Cc) * COc + j]);
      ov.f[jj] = acc;
    }
    float* ap = aW + (size_t)rr * CPWc + sub * 8;
    *reinterpret_cast<float4*>(ap) = o0.v;
    *reinterpret_cast<float4*>(ap + 4) = o1.v;
    *reinterpret_cast<float4*>(aV + (size_t)rr * COc + sub * 4) = ov.v;
  } else {
    float cw[8];
    float cv4[4];
#pragma unroll
    for (int jj = 0; jj < 8; ++jj) {
      const int j = sub * 8 + jj;
      float acc = 0.f;
#pragma unroll
      for (int i = 0; i < Cc; ++i) acc += x[i] * sw1[(i + Cc) * CPWc + j];
      cw[jj] = acc;
    }
#pragma unroll
    for (int jj = 0; jj < 4; ++jj) {
      const int j = sub * 4 + jj;
      float acc = 0.f;
#pragma unroll
      for (int i = 0; i < Cc; ++i) acc += x[i] * sv1[(i + Cc) * COc + j];
      cv4[jj] = acc;
    }
    const int bb = rr / Nk;
    const int kk = rr - bb * Nk;
    const int T = kk >> 4, mm = kk & 15;
    ushort* tp = cP + ((size_t)bb * (Nk >> 4) + T) * TFH;
    // cW octet (g == sub): 8 f16 = two 8B stores.
    ushort4 h0, h1;
    h0.x = f2h(cw[0]); h0.y = f2h(cw[1]); h0.z = f2h(cw[2]); h0.w = f2h(cw[3]);
    h1.x = f2h(cw[4]); h1.y = f2h(cw[5]); h1.z = f2h(cw[6]); h1.w = f2h(cw[7]);
    ushort* wp = tp + (sub * 16 + mm) * 8;
    *reinterpret_cast<ushort4*>(wp) = h0;
    *reinterpret_cast<ushort4*>(wp + 4) = h1;
    // cV quad: j in [sub*4, sub*4+4) -> gg = sub>>1, half = sub&1.
    ushort4 hv;
    hv.x = f2h(cv4[0]); hv.y = f2h(cv4[1]); hv.z = f2h(cv4[2]); hv.w = f2h(cv4[3]);
    const int gg = sub >> 1, half = sub & 1;
    *reinterpret_cast<ushort4*>(tp + 512 + (gg * 16 + mm) * 8 + half * 4) = hv;
  }
}

// ---------------------------------------------------------------------------
// Kernel 2 (MFMA, f16): one block per TWO consecutive rows, 256 threads =
// 4 waves; wave w owns k-quarter w (16 tiles), BOTH rows share each tile
// load (validated r13/r15). R18/19 change: 256-thread blocks instead of
// 512. Rationale: at ~70-90 VGPR, ~6 waves/SIMD fit -> a 512-thr (8-wave)
// block allows only 3 blocks/CU co-resident vs 4 needed -> the grid ran as
// ~1.33 residency rounds + 1/3-occupancy tail, masking every inner-loop
// optimization (r15/r17 nulls). 4-wave blocks -> 6 blocks/CU >= 4 nominal
// -> whole grid resident in ONE round, no tail.
// Also: w2f pre-scaled by LOG2E -> p = exp2f(relu(lgD)) (one v_exp, no
// mul; relu commutes with positive scale). cbW = b2*LOG2E.
// Fragment math, replicated-w2 (no shfl), bias-in-C, l-accum on m&3==0,
// depth-1 prefetch: all validated r8-r17. Plain exp-sum softmax (logits
// ReLU'd >= 0). No launch-bounds cap (r2-r7 law: cap -> spill).
// ---------------------------------------------------------------------------
__global__ __launch_bounds__(MTH) void ppa_main_mfma(
    const float* __restrict__ aW, const float* __restrict__ aV,
    const ushort* __restrict__ cP,
    const ushort* __restrict__ w2f, const float* __restrict__ b2,
    const ushort* __restrict__ v2f, const float* __restrict__ bv2,
    float* __restrict__ out, int N, int Nk) {
  __shared__ float sro[4][2][COc];
  __shared__ float srl[4][2][Hh];

  const int t = threadIdx.x;
  const int lane = t & 63, w = t >> 6;   // w = k-quarter
  const int m = lane & 15;
  const int g = lane >> 4;
  const int gg = g & 1;
  const int l31 = lane & 31;
  const int hh = m >> 2;
  const int row0 = blockIdx.x * 2;
  const int b = row0 / N;     // both rows in same batch (N even)

  // Loop-invariant per-lane data for BOTH rows, converted once to f16.
  f16x2 a0_0, a0_1, a0_2, a0_3, av0_0, av0_1, av0_2, av0_3;
  f16x2 a1_0, a1_1, a1_2, a1_3, av1_0, av1_1, av1_2, av1_3;
  {
    const float* aR0 = aW + (size_t)row0 * CPWc + g * 8;
    const float* aR1 = aW + (size_t)(row0 + 1) * CPWc + g * 8;
    F4 v0, v1, u0, u1;
    v0.v = *reinterpret_cast<const float4*>(aR0);
    v1.v = *reinterpret_cast<const float4*>(aR0 + 4);
    u0.v = *reinterpret_cast<const float4*>(aR1);
    u1.v = *reinterpret_cast<const float4*>(aR1 + 4);
    a0_0 = f16x2{(_Float16)v0.f[0], (_Float16)v0.f[1]};
    a0_1 = f16x2{(_Float16)v0.f[2], (_Float16)v0.f[3]};
    a0_2 = f16x2{(_Float16)v1.f[0], (_Float16)v1.f[1]};
    a0_3 = f16x2{(_Float16)v1.f[2], (_Float16)v1.f[3]};
    a1_0 = f16x2{(_Float16)u0.f[0], (_Float16)u0.f[1]};
    a1_1 = f16x2{(_Float16)u0.f[2], (_Float16)u0.f[3]};
    a1_2 = f16x2{(_Float16)u1.f[0], (_Float16)u1.f[1]};
    a1_3 = f16x2{(_Float16)u1.f[2], (_Float16)u1.f[3]};
    const float* vR0 = aV + (size_t)row0 * COc + gg * 8;
    const float* vR1 = aV + (size_t)(row0 + 1) * COc + gg * 8;
    F4 w0, w1v, x0, x1;
    w0.v = *reinterpret_cast<const float4*>(vR0);
    w1v.v = *reinterpret_cast<const float4*>(vR0 + 4);
    x0.v = *reinterpret_cast<const float4*>(vR1);
    x1.v = *reinterpret_cast<const float4*>(vR1 + 4);
    av0_0 = f16x2{(_Float16)w0.f[0], (_Float16)w0.f[1]};
    av0_1 = f16x2{(_Float16)w0.f[2], (_Float16)w0.f[3]};
    av0_2 = f16x2{(_Float16)w1v.f[0], (_Float16)w1v.f[1]};
    av0_3 = f16x2{(_Float16)w1v.f[2], (_Float16)w1v.f[3]};
    av1_0 = f16x2{(_Float16)x0.f[0], (_Float16)x0.f[1]};
    av1_1 = f16x2{(_Float16)x0.f[2], (_Float16)x0.f[3]};
    av1_2 = f16x2{(_Float16)x1.f[0], (_Float16)x1.f[1]};
    av1_3 = f16x2{(_Float16)x1.f[2], (_Float16)x1.f[3]};
  }
  const f16x8 wfrag = *reinterpret_cast<const f16x8*>(w2f + lane * 8);
  const f16x8 vfrag = *reinterpret_cast<const f16x8*>(v2f + lane * 8);
  const float b2h = b2[hh] * LOG2E;   // match the LOG2E-scaled w2f
  const float bv2c = bv2[m];
  const f32x4v cbW = {b2h, b2h, b2h, b2h};
  const f32x4v cbV = {bv2c, bv2c, bv2c, bv2c};

  float o0 = 0.f, l0 = 0.f, o1 = 0.f, l1 = 0.f;

  // Wave's packed tile base: tiles T = w*16 + s, s in [0,16).
  const ushort* tb =
      cP + ((size_t)b * (Nk >> 4) + (size_t)w * 16) * TFH;

  // ---- software pipeline, depth 1 (validated r15; depth-2 was null r17).
  H8 cw, cv;
  cw.f4 = *reinterpret_cast<const float4*>(tb + lane * 8);
  cv.f4 = *reinterpret_cast<const float4*>(tb + 512 + l31 * 8);

#pragma unroll
  for (int s = 0; s < 16; ++s) {
    H8 nw, nv;
    nw.f4 = float4{0.f, 0.f, 0.f, 0.f};
    nv.f4 = float4{0.f, 0.f, 0.f, 0.f};
    if (s < 15) {
      const ushort* nb = tb + (size_t)(s + 1) * TFH;
      nw.f4 = *reinterpret_cast<const float4*>(nb + lane * 8);
      nv.f4 = *reinterpret_cast<const float4*>(nb + 512 + l31 * 8);
    }

    // ---- logits, row 0 and row 1 (shared cw); lgD is pre-scaled by
    //      LOG2E (w2f, b2h) -> p = exp2f(relu(lgD)).
    H8 fw0, fw1;
    fw0.p.q0 = relu2(a0_0 + cw.p.q0);
    fw0.p.q1 = relu2(a0_1 + cw.p.q1);
    fw0.p.q2 = relu2(a0_2 + cw.p.q2);
    fw0.p.q3 = relu2(a0_3 + cw.p.q3);
    const f32x4v lg0 =
        __builtin_amdgcn_mfma_f32_16x16x32_f16(fw0.v8, wfrag, cbW, 0, 0, 0);
    fw1.p.q0 = relu2(a1_0 + cw.p.q0);
    fw1.p.q1 = relu2(a1_1 + cw.p.q1);
    fw1.p.q2 = relu2(a1_2 + cw.p.q2);
    fw1.p.q3 = relu2(a1_3 + cw.p.q3);
    const f32x4v lg1 =
        __builtin_amdgcn_mfma_f32_16x16x32_f16(fw1.v8, wfrag, cbW, 0, 0, 0);

    const float p00 = exp2f(fmaxf(lg0[0], 0.f));
    const float p01 = exp2f(fmaxf(lg0[1], 0.f));
    const float p02 = exp2f(fmaxf(lg0[2], 0.f));
    const float p03 = exp2f(fmaxf(lg0[3], 0.f));
    const float p10 = exp2f(fmaxf(lg1[0], 0.f));
    const float p11 = exp2f(fmaxf(lg1[1], 0.f));
    const float p12 = exp2f(fmaxf(lg1[2], 0.f));
    const float p13 = exp2f(fmaxf(lg1[3], 0.f));
    if ((m & 3) == 0) {
      l0 += (p00 + p01) + (p02 + p03);
      l1 += (p10 + p11) + (p12 + p13);
    }

    // ---- values, row 0 and row 1 (shared cv; v2f = 0.5*v2 in both
    //      K-halves, A duplicates hv -> exact).
    H8 fv0, fv1;
    fv0.p.q0 = relu2(av0_0 + cv.p.q0);
    fv0.p.q1 = relu2(av0_1 + cv.p.q1);
    fv0.p.q2 = relu2(av0_2 + cv.p.q2);
    fv0.p.q3 = relu2(av0_3 + cv.p.q3);
    const f32x4v vD0 =
        __builtin_amdgcn_mfma_f32_16x16x32_f16(fv0.v8, vfrag, cbV, 0, 0, 0);
    fv1.p.q0 = relu2(av1_0 + cv.p.q0);
    fv1.p.q1 = relu2(av1_1 + cv.p.q1);
    fv1.p.q2 = relu2(av1_2 + cv.p.q2);
    fv1.p.q3 = relu2(av1_3 + cv.p.q3);
    const f32x4v vD1 =
        __builtin_amdgcn_mfma_f32_16x16x32_f16(fv1.v8, vfrag, cbV, 0, 0, 0);

    o0 += p00 * fmaxf(vD0[0], 0.f);
    o0 += p01 * fmaxf(vD0[1], 0.f);
    o0 += p02 * fmaxf(vD0[2], 0.f);
    o0 += p03 * fmaxf(vD0[3], 0.f);
    o1 += p10 * fmaxf(vD1[0], 0.f);
    o1 += p11 * fmaxf(vD1[1], 0.f);
    o1 += p12 * fmaxf(vD1[2], 0.f);
    o1 += p13 * fmaxf(vD1[3], 0.f);

    cw = nw; cv = nv;
  }

  // ---- reduce over g-groups (xor 16/32 preserves m), then across waves.
  o0 += __shfl_xor(o0, 16);
  o0 += __shfl_xor(o0, 32);
  o1 += __shfl_xor(o1, 16);
  o1 += __shfl_xor(o1, 32);
  l0 += __shfl_xor(l0, 16);
  l0 += __shfl_xor(l0, 32);
  l1 += __shfl_xor(l1, 16);
  l1 += __shfl_xor(l1, 32);
  if (lane < COc) { sro[w][0][m] = o0; sro[w][1][m] = o1; }
  if (lane < COc && (lane & 3) == 0) {
    srl[w][0][lane >> 2] = l0;
    srl[w][1][lane >> 2] = l1;
  }
  __syncthreads();

  if (t < 2 * COc) {
    const int r = t >> 4, c = t & 15, h = c >> 2;
    float osum = 0.f, lsum = 0.f;
#pragma unroll
    for (int ww = 0; ww < 4; ++ww) {
      osum += sro[ww][r][c];
      lsum += srl[ww][r][h];
    }
    out[(size_t)(row0 + r) * COc + c] = osum / lsum;
  }
}

// ---------------------------------------------------------------------------
extern "C" void kernel_launch(void* const* d_in, const int* in_sizes, int n_in,
                              void* d_out, int out_size, void* d_ws, size_t ws_size,
                              hipStream_t stream) {
  const float* xq  = (const float*)d_in[0];
  const float* xk  = (const float*)d_in[1];
  const float* w1  = (const float*)d_in[2];
  const float* b1  = (const float*)d_in[3];
  const float* w2  = (const float*)d_in[4];
  const float* b2  = (const float*)d_in[5];
  const float* v1  = (const float*)d_in[6];
  const float* bv1 = (const float*)d_in[7];
  const float* v2  = (const float*)d_in[8];
  const float* bv2 = (const float*)d_in[9];
  float* out = (float*)d_out;

  const int BN = in_sizes[0] / Cc;  // B*N  = 2048
  const int BK = in_sizes[1] / Cc;  // B*Nk = 2048
  const int B = 2;                  // fixed by setup_inputs
  const int N = BN / B;
  const int Nk = BK / B;

  float* ws = (float*)d_ws;
  float* aW = ws;                              // BN*32 f32
  float* aV = aW + (size_t)BN * CPWc;          // BN*16 f32
  ushort* cP = (ushort*)(aV + (size_t)BN * COc);  // BK*48 f16 (packed tiles)
  ushort* w2f = cP + (size_t)BK * 48;             // 64*8 f16
  ushort* v2f = w2f + 64 * 8;                     // 64*8 f16

  const int totalRows = BN + BK;
  const int nRowBlocks = (totalRows + 63) / 64;   // 4 threads per row
  ppa_precompute<<<nRowBlocks + 1, NTH, 0, stream>>>(
      xq, xk, w1, b1, v1, bv1, w2, v2,
      aW, aV, cP, w2f, v2f, BN, BK, Nk, nRowBlocks);
  ppa_main_mfma<<<BN / 2, MTH, 0, stream>>>(aW, aV, cP, w2f, b2, v2f, bv2,
                                            out, N, Nk);
}

// Round 20
// 28.429 us; speedup vs baseline: 1.2896x; 1.2896x over previous
//
#include <hip/hip_runtime.h>
#include <hip/hip_bf16.h>
#include <math.h>

// Problem constants (fixed by setup_inputs)
static constexpr int Cc   = 16;   // C
static constexpr int COc  = 16;   // CO
static constexpr int Hh   = 4;    // heads
static constexpr int CPWc = 32;   // 2*C
static constexpr int NTH  = 256;  // precompute block size
static constexpr int MTH  = 512;  // main block size (8 waves, 2 rows)
static constexpr int TFH  = 768;  // f16 elements per packed 16-k tile (1.5 KB)
static constexpr float LOG2E = 1.44269504088896340736f;

typedef _Float16 f16x2 __attribute__((ext_vector_type(2)));
typedef _Float16 f16x8 __attribute__((ext_vector_type(8)));   // 4 VGPR
typedef __attribute__((ext_vector_type(4))) float f32x4v;     // MFMA C/D

union F4 { float4 v; float f[4]; };
// f16 octet with fully NAMED pair members (no runtime-indexed ext_vector
// arrays -> no scratch demotion; r3 lesson).
union H8 {
  f16x8 v8;
  struct { f16x2 q0, q1, q2, q3; } p;
  float4 f4;
};

__device__ __forceinline__ ushort f2h(float x) {
  _Float16 h = (_Float16)x;
  ushort u;
  __builtin_memcpy(&u, &h, 2);
  return u;
}
__device__ __forceinline__ f16x2 relu2(f16x2 x) {
  return __builtin_elementwise_max(x, (f16x2)(_Float16)0);
}

// ---------------------------------------------------------------------------
// Kernel 1: per-row first-layer projections (fp32 math, validated r1-r19),
// 4 threads per row; cP stored in F16 (validated r14-r19).
// cP f16 layout per 16-k tile (768 f16 = 1.5 KB):
//   [  0,512): lane l=g*16+m -> cW[k=T*16+m][g*8 .. g*8+8) as 8 f16 (16B)
//   [512,768): lane l&31     -> cV[k][gg*8 .. gg*8+8)      (gg = (l>>4)&1)
// Pack block (nRowBlocks): w2f REPLICATED cols B[k][n] = w2[k][n>>2],
// SCALED by LOG2E (exp(relu(x)) = exp2(relu(x*log2e)); relu commutes with
// positive scaling -> main uses exp2f = v_exp_f32, one fewer v_mul per p);
// v2f = 0.5*v2 duplicated into both K-halves (A duplicates hv -> exact).
// R16: cooperative fusion FAILED on this harness -> two kernels mandatory.
// R19: 256-thr main blocks halved wave count -> 36.7us regression; TLP
// (8192 waves) dominates residency-round neatness. Keep 512-thr blocks.
// ---------------------------------------------------------------------------
__global__ __launch_bounds__(NTH) void ppa_precompute(
    const float* __restrict__ xq, const float* __restrict__ xk,
    const float* __restrict__ w1, const float* __restrict__ b1,
    const float* __restrict__ v1, const float* __restrict__ bv1,
    const float* __restrict__ w2, const float* __restrict__ v2,
    float* __restrict__ aW, float* __restrict__ aV,
    ushort* __restrict__ cP,
    ushort* __restrict__ w2f, ushort* __restrict__ v2f,
    int BN, int BK, int Nk, int nRowBlocks) {
  const int t = threadIdx.x;

  if (blockIdx.x == nRowBlocks) {  // packing block
    if (t < 64) {
      const int n = t & 15, g = t >> 4;
#pragma unroll
      for (int i = 0; i < 8; ++i) {
        const int k = g * 8 + i;
        w2f[t * 8 + i] = f2h(LOG2E * w2[k * Hh + (n >> 2)]);  // replicated+scaled
        v2f[t * 8 + i] = f2h(0.5f * v2[(k & 15) * COc + n]);
      }
    }
    return;
  }

  __shared__ float sw1[CPWc * CPWc];
  __shared__ float sv1[CPWc * COc];
  __shared__ float sb1[CPWc];
  __shared__ float sbv1[COc];
  for (int i = t; i < CPWc * CPWc; i += NTH) sw1[i] = w1[i];
  for (int i = t; i < CPWc * COc; i += NTH) sv1[i] = v1[i];
  if (t < CPWc) sb1[t] = b1[t];
  if (t < COc) sbv1[t] = bv1[t];
  __syncthreads();

  const int r = blockIdx.x * 64 + (t >> 2);
  const int sub = t & 3;
  if (r >= BN + BK) return;
  const bool isQ = (r < BN);
  const int rr = isQ ? r : (r - BN);
  const float* src = isQ ? (xq + (size_t)rr * Cc) : (xk + (size_t)rr * Cc);

  float x[Cc];
#pragma unroll
  for (int i = 0; i < Cc; i += 4) {
    float4 v = *reinterpret_cast<const float4*>(src + i);
    x[i] = v.x; x[i + 1] = v.y; x[i + 2] = v.z; x[i + 3] = v.w;
  }

  if (isQ) {
    F4 o0, o1, ov;
#pragma unroll
    for (int jj = 0; jj < 8; ++jj) {
      const int j = sub * 8 + jj;
      float acc = sb1[j];
#pragma unroll
      for (int i = 0; i < Cc; ++i)
        acc += x[i] * (sw1[i * CPWc + j] - sw1[(i + Cc) * CPWc + j]);
      if (jj < 4) o0.f[jj] = acc; else o1.f[jj - 4] = acc;
    }
#pragma unroll
    for (int jj = 0; jj < 4; ++jj) {
      const int j = sub * 4 + jj;
      float acc = sbv1[j];
#pragma unroll
      for (int i = 0; i < Cc; ++i)
        acc += x[i] * (sv1[i * COc + j] - sv1[(i + Cc) * COc + j]);
      ov.f[jj] = acc;
    }
    float* ap = aW + (size_t)rr * CPWc + sub * 8;
    *reinterpret_cast<float4*>(ap) = o0.v;
    *reinterpret_cast<float4*>(ap + 4) = o1.v;
    *reinterpret_cast<float4*>(aV + (size_t)rr * COc + sub * 4) = ov.v;
  } else {
    float cw[8];
    float cv4[4];
#pragma unroll
    for (int jj = 0; jj < 8; ++jj) {
      const int j = sub * 8 + jj;
      float acc = 0.f;
#pragma unroll
      for (int i = 0; i < Cc; ++i) acc += x[i] * sw1[(i + Cc) * CPWc + j];
      cw[jj] = acc;
    }
#pragma unroll
    for (int jj = 0; jj < 4; ++jj) {
      const int j = sub * 4 + jj;
      float acc = 0.f;
#pragma unroll
      for (int i = 0; i < Cc; ++i) acc += x[i] * sv1[(i + Cc) * COc + j];
      cv4[jj] = acc;
    }
    const int bb = rr / Nk;
    const int kk = rr - bb * Nk;
    const int T = kk >> 4, mm = kk & 15;
    ushort* tp = cP + ((size_t)bb * (Nk >> 4) + T) * TFH;
    // cW octet (g == sub): 8 f16 = two 8B stores.
    ushort4 h0, h1;
    h0.x = f2h(cw[0]); h0.y = f2h(cw[1]); h0.z = f2h(cw[2]); h0.w = f2h(cw[3]);
    h1.x = f2h(cw[4]); h1.y = f2h(cw[5]); h1.z = f2h(cw[6]); h1.w = f2h(cw[7]);
    ushort* wp = tp + (sub * 16 + mm) * 8;
    *reinterpret_cast<ushort4*>(wp) = h0;
    *reinterpret_cast<ushort4*>(wp + 4) = h1;
    // cV quad: j in [sub*4, sub*4+4) -> gg = sub>>1, half = sub&1.
    ushort4 hv;
    hv.x = f2h(cv4[0]); hv.y = f2h(cv4[1]); hv.z = f2h(cv4[2]); hv.w = f2h(cv4[3]);
    const int gg = sub >> 1, half = sub & 1;
    *reinterpret_cast<ushort4*>(tp + 512 + (gg * 16 + mm) * 8 + half * 4) = hv;
  }
}

// ---------------------------------------------------------------------------
// Kernel 2 (MFMA, f16): one block per TWO consecutive rows, 512 threads =
// 8 waves (r15 geometry, proven best 25.4us; r19's 4-wave variant halved
// TLP -> 36.7us). Wave w: k-quarter q = w&3, half = w>>2 (8 tiles), BOTH
// rows share each tile load (validated r13/r15). Depth-1 prefetch
// (depth-2 null, r17). p = exp2f(relu(lgD)) with LOG2E folded into
// w2f/b2 (r19-validated numerics, absmax unchanged 3.9e-3).
// Fragment math, replicated-w2 (no shfl), bias-in-C, l-accum on m&3==0:
// validated r8-r19. Plain exp-sum softmax (logits ReLU'd >= 0).
// No launch-bounds cap (r2-r7 law: cap = 256/arg -> scratch spill).
// ---------------------------------------------------------------------------
__global__ __launch_bounds__(MTH) void ppa_main_mfma(
    const float* __restrict__ aW, const float* __restrict__ aV,
    const ushort* __restrict__ cP,
    const ushort* __restrict__ w2f, const float* __restrict__ b2,
    const ushort* __restrict__ v2f, const float* __restrict__ bv2,
    float* __restrict__ out, int N, int Nk) {
  __shared__ float sro[8][2][COc];
  __shared__ float srl[8][2][Hh];

  const int t = threadIdx.x;
  const int lane = t & 63, w = t >> 6;
  const int q = w & 3;        // k-quarter
  const int half = w >> 2;    // half of the quarter (tiles 0-7 / 8-15)
  const int m = lane & 15;
  const int g = lane >> 4;
  const int gg = g & 1;
  const int l31 = lane & 31;
  const int hh = m >> 2;
  const int row0 = blockIdx.x * 2;
  const int b = row0 / N;     // both rows in same batch (N even)

  // Loop-invariant per-lane data for BOTH rows, converted once to f16.
  f16x2 a0_0, a0_1, a0_2, a0_3, av0_0, av0_1, av0_2, av0_3;
  f16x2 a1_0, a1_1, a1_2, a1_3, av1_0, av1_1, av1_2, av1_3;
  {
    const float* aR0 = aW + (size_t)row0 * CPWc + g * 8;
    const float* aR1 = aW + (size_t)(row0 + 1) * CPWc + g * 8;
    F4 v0, v1, u0, u1;
    v0.v = *reinterpret_cast<const float4*>(aR0);
    v1.v = *reinterpret_cast<const float4*>(aR0 + 4);
    u0.v = *reinterpret_cast<const float4*>(aR1);
    u1.v = *reinterpret_cast<const float4*>(aR1 + 4);
    a0_0 = f16x2{(_Float16)v0.f[0], (_Float16)v0.f[1]};
    a0_1 = f16x2{(_Float16)v0.f[2], (_Float16)v0.f[3]};
    a0_2 = f16x2{(_Float16)v1.f[0], (_Float16)v1.f[1]};
    a0_3 = f16x2{(_Float16)v1.f[2], (_Float16)v1.f[3]};
    a1_0 = f16x2{(_Float16)u0.f[0], (_Float16)u0.f[1]};
    a1_1 = f16x2{(_Float16)u0.f[2], (_Float16)u0.f[3]};
    a1_2 = f16x2{(_Float16)u1.f[0], (_Float16)u1.f[1]};
    a1_3 = f16x2{(_Float16)u1.f[2], (_Float16)u1.f[3]};
    const float* vR0 = aV + (size_t)row0 * COc + gg * 8;
    const float* vR1 = aV + (size_t)(row0 + 1) * COc + gg * 8;
    F4 w0, w1v, x0, x1;
    w0.v = *reinterpret_cast<const float4*>(vR0);
    w1v.v = *reinterpret_cast<const float4*>(vR0 + 4);
    x0.v = *reinterpret_cast<const float4*>(vR1);
    x1.v = *reinterpret_cast<const float4*>(vR1 + 4);
    av0_0 = f16x2{(_Float16)w0.f[0], (_Float16)w0.f[1]};
    av0_1 = f16x2{(_Float16)w0.f[2], (_Float16)w0.f[3]};
    av0_2 = f16x2{(_Float16)w1v.f[0], (_Float16)w1v.f[1]};
    av0_3 = f16x2{(_Float16)w1v.f[2], (_Float16)w1v.f[3]};
    av1_0 = f16x2{(_Float16)x0.f[0], (_Float16)x0.f[1]};
    av1_1 = f16x2{(_Float16)x0.f[2], (_Float16)x0.f[3]};
    av1_2 = f16x2{(_Float16)x1.f[0], (_Float16)x1.f[1]};
    av1_3 = f16x2{(_Float16)x1.f[2], (_Float16)x1.f[3]};
  }
  const f16x8 wfrag = *reinterpret_cast<const f16x8*>(w2f + lane * 8);
  const f16x8 vfrag = *reinterpret_cast<const f16x8*>(v2f + lane * 8);
  const float b2h = b2[hh] * LOG2E;   // match the LOG2E-scaled w2f
  const float bv2c = bv2[m];
  const f32x4v cbW = {b2h, b2h, b2h, b2h};
  const f32x4v cbV = {bv2c, bv2c, bv2c, bv2c};

  float o0 = 0.f, l0 = 0.f, o1 = 0.f, l1 = 0.f;

  // Wave's packed tile base: tiles T = q*16 + half*8 + s, s in [0,8).
  const ushort* tb =
      cP + ((size_t)b * (Nk >> 4) + (size_t)q * 16 + (size_t)half * 8) * TFH;

  // ---- software pipeline, depth 1 (validated r15; depth-2 null r17).
  H8 cw, cv;
  cw.f4 = *reinterpret_cast<const float4*>(tb + lane * 8);
  cv.f4 = *reinterpret_cast<const float4*>(tb + 512 + l31 * 8);

#pragma unroll
  for (int s = 0; s < 8; ++s) {
    H8 nw, nv;
    nw.f4 = float4{0.f, 0.f, 0.f, 0.f};
    nv.f4 = float4{0.f, 0.f, 0.f, 0.f};
    if (s < 7) {
      const ushort* nb = tb + (size_t)(s + 1) * TFH;
      nw.f4 = *reinterpret_cast<const float4*>(nb + lane * 8);
      nv.f4 = *reinterpret_cast<const float4*>(nb + 512 + l31 * 8);
    }

    // ---- logits, row 0 and row 1 (shared cw); lgD pre-scaled by LOG2E
    //      (w2f, b2h) -> p = exp2f(relu(lgD)).
    H8 fw0, fw1;
    fw0.p.q0 = relu2(a0_0 + cw.p.q0);
    fw0.p.q1 = relu2(a0_1 + cw.p.q1);
    fw0.p.q2 = relu2(a0_2 + cw.p.q2);
    fw0.p.q3 = relu2(a0_3 + cw.p.q3);
    const f32x4v lg0 =
        __builtin_amdgcn_mfma_f32_16x16x32_f16(fw0.v8, wfrag, cbW, 0, 0, 0);
    fw1.p.q0 = relu2(a1_0 + cw.p.q0);
    fw1.p.q1 = relu2(a1_1 + cw.p.q1);
    fw1.p.q2 = relu2(a1_2 + cw.p.q2);
    fw1.p.q3 = relu2(a1_3 + cw.p.q3);
    const f32x4v lg1 =
        __builtin_amdgcn_mfma_f32_16x16x32_f16(fw1.v8, wfrag, cbW, 0, 0, 0);

    const float p00 = exp2f(fmaxf(lg0[0], 0.f));
    const float p01 = exp2f(fmaxf(lg0[1], 0.f));
    const float p02 = exp2f(fmaxf(lg0[2], 0.f));
    const float p03 = exp2f(fmaxf(lg0[3], 0.f));
    const float p10 = exp2f(fmaxf(lg1[0], 0.f));
    const float p11 = exp2f(fmaxf(lg1[1], 0.f));
    const float p12 = exp2f(fmaxf(lg1[2], 0.f));
    const float p13 = exp2f(fmaxf(lg1[3], 0.f));
    if ((m & 3) == 0) {
      l0 += (p00 + p01) + (p02 + p03);
      l1 += (p10 + p11) + (p12 + p13);
    }

    // ---- values, row 0 and row 1 (shared cv; v2f = 0.5*v2 in both
    //      K-halves, A duplicates hv -> exact).
    H8 fv0, fv1;
    fv0.p.q0 = relu2(av0_0 + cv.p.q0);
    fv0.p.q1 = relu2(av0_1 + cv.p.q1);
    fv0.p.q2 = relu2(av0_2 + cv.p.q2);
    fv0.p.q3 = relu2(av0_3 + cv.p.q3);
    const f32x4v vD0 =
        __builtin_amdgcn_mfma_f32_16x16x32_f16(fv0.v8, vfrag, cbV, 0, 0, 0);
    fv1.p.q0 = relu2(av1_0 + cv.p.q0);
    fv1.p.q1 = relu2(av1_1 + cv.p.q1);
    fv1.p.q2 = relu2(av1_2 + cv.p.q2);
    fv1.p.q3 = relu2(av1_3 + cv.p.q3);
    const f32x4v vD1 =
        __builtin_amdgcn_mfma_f32_16x16x32_f16(fv1.v8, vfrag, cbV, 0, 0, 0);

    o0 += p00 * fmaxf(vD0[0], 0.f);
    o0 += p01 * fmaxf(vD0[1], 0.f);
    o0 += p02 * fmaxf(vD0[2], 0.f);
    o0 += p03 * fmaxf(vD0[3], 0.f);
    o1 += p10 * fmaxf(vD1[0], 0.f);
    o1 += p11 * fmaxf(vD1[1], 0.f);
    o1 += p12 * fmaxf(vD1[2], 0.f);
    o1 += p13 * fmaxf(vD1[3], 0.f);

    cw = nw; cv = nv;
  }

  // ---- reduce over g-groups (xor 16/32 preserves m), then across waves.
  o0 += __shfl_xor(o0, 16);
  o0 += __shfl_xor(o0, 32);
  o1 += __shfl_xor(o1, 16);
  o1 += __shfl_xor(o1, 32);
  l0 += __shfl_xor(l0, 16);
  l0 += __shfl_xor(l0, 32);
  l1 += __shfl_xor(l1, 16);
  l1 += __shfl_xor(l1, 32);
  if (lane < COc) { sro[w][0][m] = o0; sro[w][1][m] = o1; }
  if (lane < COc && (lane & 3) == 0) {
    srl[w][0][lane >> 2] = l0;
    srl[w][1][lane >> 2] = l1;
  }
  __syncthreads();

  if (t < 2 * COc) {
    const int r = t >> 4, c = t & 15, h = c >> 2;
    float osum = 0.f, lsum = 0.f;
#pragma unroll
    for (int ww = 0; ww < 8; ++ww) {
      osum += sro[ww][r][c];
      lsum += srl[ww][r][h];
    }
    out[(size_t)(row0 + r) * COc + c] = osum / lsum;
  }
}

// ---------------------------------------------------------------------------
extern "C" void kernel_launch(void* const* d_in, const int* in_sizes, int n_in,
                              void* d_out, int out_size, void* d_ws, size_t ws_size,
                              hipStream_t stream) {
  const float* xq  = (const float*)d_in[0];
  const float* xk  = (const float*)d_in[1];
  const float* w1  = (const float*)d_in[2];
  const float* b1  = (const float*)d_in[3];
  const float* w2  = (const float*)d_in[4];
  const float* b2  = (const float*)d_in[5];
  const float* v1  = (const float*)d_in[6];
  const float* bv1 = (const float*)d_in[7];
  const float* v2  = (const float*)d_in[8];
  const float* bv2 = (const float*)d_in[9];
  float* out = (float*)d_out;

  const int BN = in_sizes[0] / Cc;  // B*N  = 2048
  const int BK = in_sizes[1] / Cc;  // B*Nk = 2048
  const int B = 2;                  // fixed by setup_inputs
  const int N = BN / B;
  const int Nk = BK / B;

  float* ws = (float*)d_ws;
  float* aW = ws;                              // BN*32 f32
  float* aV = aW + (size_t)BN * CPWc;          // BN*16 f32
  ushort* cP = (ushort*)(aV + (size_t)BN * COc);  // BK*48 f16 (packed tiles)
  ushort* w2f = cP + (size_t)BK * 48;             // 64*8 f16
  ushort* v2f = w2f + 64 * 8;                     // 64*8 f16

  const int totalRows = BN + BK;
  const int nRowBlocks = (totalRows + 63) / 64;   // 4 threads per row
  ppa_precompute<<<nRowBlocks + 1, NTH, 0, stream>>>(
      xq, xk, w1, b1, v1, bv1, w2, v2,
      aW, aV, cP, w2f, v2f, BN, BK, Nk, nRowBlocks);
  ppa_main_mfma<<<BN / 2, MTH, 0, stream>>>(aW, aV, cP, w2f, b2, v2f, bv2,
                                            out, N, Nk);
}

// Round 21
// 24.825 us; speedup vs baseline: 1.4768x; 1.1452x over previous
//
#include <hip/hip_runtime.h>
#include <hip/hip_bf16.h>
#include <math.h>

// Problem constants (fixed by setup_inputs)
static constexpr int Cc   = 16;   // C
static constexpr int COc  = 16;   // CO
static constexpr int Hh   = 4;    // heads
static constexpr int CPWc = 32;   // 2*C
static constexpr int NTH  = 256;  // precompute block size
static constexpr int MTH  = 512;  // main block size (8 waves, 2 rows)
static constexpr int TFH  = 768;  // f16 elements per packed 16-k tile (1.5 KB)
static constexpr float LOG2E = 1.44269504088896340736f;

typedef _Float16 f16x2 __attribute__((ext_vector_type(2)));
typedef _Float16 f16x8 __attribute__((ext_vector_type(8)));   // 4 VGPR
typedef __attribute__((ext_vector_type(4))) float f32x4v;     // MFMA C/D

union F4 { float4 v; float f[4]; };
// f16 octet with fully NAMED pair members (no runtime-indexed ext_vector
// arrays -> no scratch demotion; r3 lesson).
union H8 {
  f16x8 v8;
  struct { f16x2 q0, q1, q2, q3; } p;
  float4 f4;
};

__device__ __forceinline__ ushort f2h(float x) {
  _Float16 h = (_Float16)x;
  ushort u;
  __builtin_memcpy(&u, &h, 2);
  return u;
}
__device__ __forceinline__ f16x2 relu2(f16x2 x) {
  return __builtin_elementwise_max(x, (f16x2)(_Float16)0);
}
// Raw v_exp_f32 (1 instruction). exp2f() is libm (range-checked, slow —
// r20's 3us regression); __expf() is v_mul+v_exp. This is the fast path.
__device__ __forceinline__ float fexp2(float x) {
  return __builtin_amdgcn_exp2f(x);
}

// ---------------------------------------------------------------------------
// Kernel 1: per-row first-layer projections (fp32 math, validated r1-r20),
// 4 threads per row; cP stored in F16 (validated r14-r20).
// cP f16 layout per 16-k tile (768 f16 = 1.5 KB):
//   [  0,512): lane l=g*16+m -> cW[k=T*16+m][g*8 .. g*8+8) as 8 f16 (16B)
//   [512,768): lane l&31     -> cV[k][gg*8 .. gg*8+8)      (gg = (l>>4)&1)
// Pack block (nRowBlocks): w2f REPLICATED cols B[k][n] = w2[k][n>>2],
// SCALED by LOG2E (exp(relu(x)) = exp2(relu(x*log2e)); relu commutes with
// positive scaling -> main uses __builtin_amdgcn_exp2f = bare v_exp_f32);
// v2f = 0.5*v2 duplicated into both K-halves (A duplicates hv -> exact).
// R16: cooperative fusion FAILED on this harness -> two kernels mandatory.
// R19: 256-thr main blocks halved wave count -> 36.7us; keep 512-thr.
// R20: exp2f() is libm, NOT the fast intrinsic -> 28.4us; fixed here.
// ---------------------------------------------------------------------------
__global__ __launch_bounds__(NTH) void ppa_precompute(
    const float* __restrict__ xq, const float* __restrict__ xk,
    const float* __restrict__ w1, const float* __restrict__ b1,
    const float* __restrict__ v1, const float* __restrict__ bv1,
    const float* __restrict__ w2, const float* __restrict__ v2,
    float* __restrict__ aW, float* __restrict__ aV,
    ushort* __restrict__ cP,
    ushort* __restrict__ w2f, ushort* __restrict__ v2f,
    int BN, int BK, int Nk, int nRowBlocks) {
  const int t = threadIdx.x;

  if (blockIdx.x == nRowBlocks) {  // packing block
    if (t < 64) {
      const int n = t & 15, g = t >> 4;
#pragma unroll
      for (int i = 0; i < 8; ++i) {
        const int k = g * 8 + i;
        w2f[t * 8 + i] = f2h(LOG2E * w2[k * Hh + (n >> 2)]);  // replicated+scaled
        v2f[t * 8 + i] = f2h(0.5f * v2[(k & 15) * COc + n]);
      }
    }
    return;
  }

  __shared__ float sw1[CPWc * CPWc];
  __shared__ float sv1[CPWc * COc];
  __shared__ float sb1[CPWc];
  __shared__ float sbv1[COc];
  for (int i = t; i < CPWc * CPWc; i += NTH) sw1[i] = w1[i];
  for (int i = t; i < CPWc * COc; i += NTH) sv1[i] = v1[i];
  if (t < CPWc) sb1[t] = b1[t];
  if (t < COc) sbv1[t] = bv1[t];
  __syncthreads();

  const int r = blockIdx.x * 64 + (t >> 2);
  const int sub = t & 3;
  if (r >= BN + BK) return;
  const bool isQ = (r < BN);
  const int rr = isQ ? r : (r - BN);
  const float* src = isQ ? (xq + (size_t)rr * Cc) : (xk + (size_t)rr * Cc);

  float x[Cc];
#pragma unroll
  for (int i = 0; i < Cc; i += 4) {
    float4 v = *reinterpret_cast<const float4*>(src + i);
    x[i] = v.x; x[i + 1] = v.y; x[i + 2] = v.z; x[i + 3] = v.w;
  }

  if (isQ) {
    F4 o0, o1, ov;
#pragma unroll
    for (int jj = 0; jj < 8; ++jj) {
      const int j = sub * 8 + jj;
      float acc = sb1[j];
#pragma unroll
      for (int i = 0; i < Cc; ++i)
        acc += x[i] * (sw1[i * CPWc + j] - sw1[(i + Cc) * CPWc + j]);
      if (jj < 4) o0.f[jj] = acc; else o1.f[jj - 4] = acc;
    }
#pragma unroll
    for (int jj = 0; jj < 4; ++jj) {
      const int j = sub * 4 + jj;
      float acc = sbv1[j];
#pragma unroll
      for (int i = 0; i < Cc; ++i)
        acc += x[i] * (sv1[i * COc + j] - sv1[(i + Cc) * COc + j]);
      ov.f[jj] = acc;
    }
    float* ap = aW + (size_t)rr * CPWc + sub * 8;
    *reinterpret_cast<float4*>(ap) = o0.v;
    *reinterpret_cast<float4*>(ap + 4) = o1.v;
    *reinterpret_cast<float4*>(aV + (size_t)rr * COc + sub * 4) = ov.v;
  } else {
    float cw[8];
    float cv4[4];
#pragma unroll
    for (int jj = 0; jj < 8; ++jj) {
      const int j = sub * 8 + jj;
      float acc = 0.f;
#pragma unroll
      for (int i = 0; i < Cc; ++i) acc += x[i] * sw1[(i + Cc) * CPWc + j];
      cw[jj] = acc;
    }
#pragma unroll
    for (int jj = 0; jj < 4; ++jj) {
      const int j = sub * 4 + jj;
      float acc = 0.f;
#pragma unroll
      for (int i = 0; i < Cc; ++i) acc += x[i] * sv1[(i + Cc) * COc + j];
      cv4[jj] = acc;
    }
    const int bb = rr / Nk;
    const int kk = rr - bb * Nk;
    const int T = kk >> 4, mm = kk & 15;
    ushort* tp = cP + ((size_t)bb * (Nk >> 4) + T) * TFH;
    // cW octet (g == sub): 8 f16 = two 8B stores.
    ushort4 h0, h1;
    h0.x = f2h(cw[0]); h0.y = f2h(cw[1]); h0.z = f2h(cw[2]); h0.w = f2h(cw[3]);
    h1.x = f2h(cw[4]); h1.y = f2h(cw[5]); h1.z = f2h(cw[6]); h1.w = f2h(cw[7]);
    ushort* wp = tp + (sub * 16 + mm) * 8;
    *reinterpret_cast<ushort4*>(wp) = h0;
    *reinterpret_cast<ushort4*>(wp + 4) = h1;
    // cV quad: j in [sub*4, sub*4+4) -> gg = sub>>1, half = sub&1.
    ushort4 hv;
    hv.x = f2h(cv4[0]); hv.y = f2h(cv4[1]); hv.z = f2h(cv4[2]); hv.w = f2h(cv4[3]);
    const int gg = sub >> 1, half = sub & 1;
    *reinterpret_cast<ushort4*>(tp + 512 + (gg * 16 + mm) * 8 + half * 4) = hv;
  }
}

// ---------------------------------------------------------------------------
// Kernel 2 (MFMA, f16): one block per TWO consecutive rows, 512 threads =
// 8 waves (r15 geometry, proven best; r19's 4-wave variant halved TLP ->
// 36.7us). Wave w: k-quarter q = w&3, half = w>>2 (8 tiles), BOTH rows
// share each tile load (validated r13/r15). Depth-1 prefetch (depth-2
// null, r17). p = v_exp_f32(relu(lgD)) with LOG2E folded into w2f/b2.
// Fragment math, replicated-w2 (no shfl), bias-in-C, l-accum on m&3==0:
// validated r8-r20. Plain exp-sum softmax (logits ReLU'd >= 0).
// No launch-bounds cap (r2-r7 law: cap = 256/arg -> scratch spill).
// ---------------------------------------------------------------------------
__global__ __launch_bounds__(MTH) void ppa_main_mfma(
    const float* __restrict__ aW, const float* __restrict__ aV,
    const ushort* __restrict__ cP,
    const ushort* __restrict__ w2f, const float* __restrict__ b2,
    const ushort* __restrict__ v2f, const float* __restrict__ bv2,
    float* __restrict__ out, int N, int Nk) {
  __shared__ float sro[8][2][COc];
  __shared__ float srl[8][2][Hh];

  const int t = threadIdx.x;
  const int lane = t & 63, w = t >> 6;
  const int q = w & 3;        // k-quarter
  const int half = w >> 2;    // half of the quarter (tiles 0-7 / 8-15)
  const int m = lane & 15;
  const int g = lane >> 4;
  const int gg = g & 1;
  const int l31 = lane & 31;
  const int hh = m >> 2;
  const int row0 = blockIdx.x * 2;
  const int b = row0 / N;     // both rows in same batch (N even)

  // Loop-invariant per-lane data for BOTH rows, converted once to f16.
  f16x2 a0_0, a0_1, a0_2, a0_3, av0_0, av0_1, av0_2, av0_3;
  f16x2 a1_0, a1_1, a1_2, a1_3, av1_0, av1_1, av1_2, av1_3;
  {
    const float* aR0 = aW + (size_t)row0 * CPWc + g * 8;
    const float* aR1 = aW + (size_t)(row0 + 1) * CPWc + g * 8;
    F4 v0, v1, u0, u1;
    v0.v = *reinterpret_cast<const float4*>(aR0);
    v1.v = *reinterpret_cast<const float4*>(aR0 + 4);
    u0.v = *reinterpret_cast<const float4*>(aR1);
    u1.v = *reinterpret_cast<const float4*>(aR1 + 4);
    a0_0 = f16x2{(_Float16)v0.f[0], (_Float16)v0.f[1]};
    a0_1 = f16x2{(_Float16)v0.f[2], (_Float16)v0.f[3]};
    a0_2 = f16x2{(_Float16)v1.f[0], (_Float16)v1.f[1]};
    a0_3 = f16x2{(_Float16)v1.f[2], (_Float16)v1.f[3]};
    a1_0 = f16x2{(_Float16)u0.f[0], (_Float16)u0.f[1]};
    a1_1 = f16x2{(_Float16)u0.f[2], (_Float16)u0.f[3]};
    a1_2 = f16x2{(_Float16)u1.f[0], (_Float16)u1.f[1]};
    a1_3 = f16x2{(_Float16)u1.f[2], (_Float16)u1.f[3]};
    const float* vR0 = aV + (size_t)row0 * COc + gg * 8;
    const float* vR1 = aV + (size_t)(row0 + 1) * COc + gg * 8;
    F4 w0, w1v, x0, x1;
    w0.v = *reinterpret_cast<const float4*>(vR0);
    w1v.v = *reinterpret_cast<const float4*>(vR0 + 4);
    x0.v = *reinterpret_cast<const float4*>(vR1);
    x1.v = *reinterpret_cast<const float4*>(vR1 + 4);
    av0_0 = f16x2{(_Float16)w0.f[0], (_Float16)w0.f[1]};
    av0_1 = f16x2{(_Float16)w0.f[2], (_Float16)w0.f[3]};
    av0_2 = f16x2{(_Float16)w1v.f[0], (_Float16)w1v.f[1]};
    av0_3 = f16x2{(_Float16)w1v.f[2], (_Float16)w1v.f[3]};
    av1_0 = f16x2{(_Float16)x0.f[0], (_Float16)x0.f[1]};
    av1_1 = f16x2{(_Float16)x0.f[2], (_Float16)x0.f[3]};
    av1_2 = f16x2{(_Float16)x1.f[0], (_Float16)x1.f[1]};
    av1_3 = f16x2{(_Float16)x1.f[2], (_Float16)x1.f[3]};
  }
  const f16x8 wfrag = *reinterpret_cast<const f16x8*>(w2f + lane * 8);
  const f16x8 vfrag = *reinterpret_cast<const f16x8*>(v2f + lane * 8);
  const float b2h = b2[hh] * LOG2E;   // match the LOG2E-scaled w2f
  const float bv2c = bv2[m];
  const f32x4v cbW = {b2h, b2h, b2h, b2h};
  const f32x4v cbV = {bv2c, bv2c, bv2c, bv2c};

  float o0 = 0.f, l0 = 0.f, o1 = 0.f, l1 = 0.f;

  // Wave's packed tile base: tiles T = q*16 + half*8 + s, s in [0,8).
  const ushort* tb =
      cP + ((size_t)b * (Nk >> 4) + (size_t)q * 16 + (size_t)half * 8) * TFH;

  // ---- software pipeline, depth 1 (validated r15; depth-2 null r17).
  H8 cw, cv;
  cw.f4 = *reinterpret_cast<const float4*>(tb + lane * 8);
  cv.f4 = *reinterpret_cast<const float4*>(tb + 512 + l31 * 8);

#pragma unroll
  for (int s = 0; s < 8; ++s) {
    H8 nw, nv;
    nw.f4 = float4{0.f, 0.f, 0.f, 0.f};
    nv.f4 = float4{0.f, 0.f, 0.f, 0.f};
    if (s < 7) {
      const ushort* nb = tb + (size_t)(s + 1) * TFH;
      nw.f4 = *reinterpret_cast<const float4*>(nb + lane * 8);
      nv.f4 = *reinterpret_cast<const float4*>(nb + 512 + l31 * 8);
    }

    // ---- logits, row 0 and row 1 (shared cw); lgD pre-scaled by LOG2E
    //      (w2f, b2h) -> p = v_exp_f32(relu(lgD)).
    H8 fw0, fw1;
    fw0.p.q0 = relu2(a0_0 + cw.p.q0);
    fw0.p.q1 = relu2(a0_1 + cw.p.q1);
    fw0.p.q2 = relu2(a0_2 + cw.p.q2);
    fw0.p.q3 = relu2(a0_3 + cw.p.q3);
    const f32x4v lg0 =
        __builtin_amdgcn_mfma_f32_16x16x32_f16(fw0.v8, wfrag, cbW, 0, 0, 0);
    fw1.p.q0 = relu2(a1_0 + cw.p.q0);
    fw1.p.q1 = relu2(a1_1 + cw.p.q1);
    fw1.p.q2 = relu2(a1_2 + cw.p.q2);
    fw1.p.q3 = relu2(a1_3 + cw.p.q3);
    const f32x4v lg1 =
        __builtin_amdgcn_mfma_f32_16x16x32_f16(fw1.v8, wfrag, cbW, 0, 0, 0);

    const float p00 = fexp2(fmaxf(lg0[0], 0.f));
    const float p01 = fexp2(fmaxf(lg0[1], 0.f));
    const float p02 = fexp2(fmaxf(lg0[2], 0.f));
    const float p03 = fexp2(fmaxf(lg0[3], 0.f));
    const float p10 = fexp2(fmaxf(lg1[0], 0.f));
    const float p11 = fexp2(fmaxf(lg1[1], 0.f));
    const float p12 = fexp2(fmaxf(lg1[2], 0.f));
    const float p13 = fexp2(fmaxf(lg1[3], 0.f));
    if ((m & 3) == 0) {
      l0 += (p00 + p01) + (p02 + p03);
      l1 += (p10 + p11) + (p12 + p13);
    }

    // ---- values, row 0 and row 1 (shared cv; v2f = 0.5*v2 in both
    //      K-halves, A duplicates hv -> exact).
    H8 fv0, fv1;
    fv0.p.q0 = relu2(av0_0 + cv.p.q0);
    fv0.p.q1 = relu2(av0_1 + cv.p.q1);
    fv0.p.q2 = relu2(av0_2 + cv.p.q2);
    fv0.p.q3 = relu2(av0_3 + cv.p.q3);
    const f32x4v vD0 =
        __builtin_amdgcn_mfma_f32_16x16x32_f16(fv0.v8, vfrag, cbV, 0, 0, 0);
    fv1.p.q0 = relu2(av1_0 + cv.p.q0);
    fv1.p.q1 = relu2(av1_1 + cv.p.q1);
    fv1.p.q2 = relu2(av1_2 + cv.p.q2);
    fv1.p.q3 = relu2(av1_3 + cv.p.q3);
    const f32x4v vD1 =
        __builtin_amdgcn_mfma_f32_16x16x32_f16(fv1.v8, vfrag, cbV, 0, 0, 0);

    o0 += p00 * fmaxf(vD0[0], 0.f);
    o0 += p01 * fmaxf(vD0[1], 0.f);
    o0 += p02 * fmaxf(vD0[2], 0.f);
    o0 += p03 * fmaxf(vD0[3], 0.f);
    o1 += p10 * fmaxf(vD1[0], 0.f);
    o1 += p11 * fmaxf(vD1[1], 0.f);
    o1 += p12 * fmaxf(vD1[2], 0.f);
    o1 += p13 * fmaxf(vD1[3], 0.f);

    cw = nw; cv = nv;
  }

  // ---- reduce over g-groups (xor 16/32 preserves m), then across waves.
  o0 += __shfl_xor(o0, 16);
  o0 += __shfl_xor(o0, 32);
  o1 += __shfl_xor(o1, 16);
  o1 += __shfl_xor(o1, 32);
  l0 += __shfl_xor(l0, 16);
  l0 += __shfl_xor(l0, 32);
  l1 += __shfl_xor(l1, 16);
  l1 += __shfl_xor(l1, 32);
  if (lane < COc) { sro[w][0][m] = o0; sro[w][1][m] = o1; }
  if (lane < COc && (lane & 3) == 0) {
    srl[w][0][lane >> 2] = l0;
    srl[w][1][lane >> 2] = l1;
  }
  __syncthreads();

  if (t < 2 * COc) {
    const int r = t >> 4, c = t & 15, h = c >> 2;
    float osum = 0.f, lsum = 0.f;
#pragma unroll
    for (int ww = 0; ww < 8; ++ww) {
      osum += sro[ww][r][c];
      lsum += srl[ww][r][h];
    }
    out[(size_t)(row0 + r) * COc + c] = osum / lsum;
  }
}

// ---------------------------------------------------------------------------
extern "C" void kernel_launch(void* const* d_in, const int* in_sizes, int n_in,
                              void* d_out, int out_size, void* d_ws, size_t ws_size,
                              hipStream_t stream) {
  const float* xq  = (const float*)d_in[0];
  const float* xk  = (const float*)d_in[1];
  const float* w1  = (const float*)d_in[2];
  const float* b1  = (const float*)d_in[3];
  const float* w2  = (const float*)d_in[4];
  const float* b2  = (const float*)d_in[5];
  const float* v1  = (const float*)d_in[6];
  const float* bv1 = (const float*)d_in[7];
  const float* v2  = (const float*)d_in[8];
  const float* bv2 = (const float*)d_in[9];
  float* out = (float*)d_out;

  const int BN = in_sizes[0] / Cc;  // B*N  = 2048
  const int BK = in_sizes[1] / Cc;  // B*Nk = 2048
  const int B = 2;                  // fixed by setup_inputs
  const int N = BN / B;
  const int Nk = BK / B;

  float* ws = (float*)d_ws;
  float* aW = ws;                              // BN*32 f32
  float* aV = aW + (size_t)BN * CPWc;          // BN*16 f32
  ushort* cP = (ushort*)(aV + (size_t)BN * COc);  // BK*48 f16 (packed tiles)
  ushort* w2f = cP + (size_t)BK * 48;             // 64*8 f16
  ushort* v2f = w2f + 64 * 8;                     // 64*8 f16

  const int totalRows = BN + BK;
  const int nRowBlocks = (totalRows + 63) / 64;   // 4 threads per row
  ppa_precompute<<<nRowBlocks + 1, NTH, 0, stream>>>(
      xq, xk, w1, b1, v1, bv1, w2, v2,
      aW, aV, cP, w2f, v2f, BN, BK, Nk, nRowBlocks);
  ppa_main_mfma<<<BN / 2, MTH, 0, stream>>>(aW, aV, cP, w2f, b2, v2f, bv2,
                                            out, N, Nk);
}